// Round 11
// baseline (208.592 us; speedup 1.0000x reference)
//
#include <hip/hip_runtime.h>
#include <hip/hip_bf16.h>
#include <hip/hip_fp16.h>

#define B_  16
#define G_  4
#define CG  64
#define H_  64
#define W_  64
#define KK  9
#define HW  (H_ * W_)
#define IP  72            // padded i-stride (shorts) for sT rows: 144 B
#define PD  68            // padded spatial dim (64 + 2 each side)
#define XSLICE (PD * PD * CG)   // shorts per (b,g) slice of xTpad

typedef short    short8  __attribute__((ext_vector_type(8)));
typedef _Float16 half8   __attribute__((ext_vector_type(8)));
typedef _Float16 h2      __attribute__((ext_vector_type(2)));
typedef float    f32x4   __attribute__((ext_vector_type(4)));
typedef float    f32x16  __attribute__((ext_vector_type(16)));

__device__ __forceinline__ short f2h(float v) {
    _Float16 h = (_Float16)v;
    short s;
    __builtin_memcpy(&s, &h, 2);
    return s;
}

__device__ __forceinline__ unsigned int pk2h(float a, float b) {
    h2 h = { (_Float16)a, (_Float16)b };
    unsigned int u;
    __builtin_memcpy(&u, &h, 4);
    return u;
}

// bilinear combine of 2 packed fp16 channels via native v_pk_fma_f16
__device__ __forceinline__ unsigned int interp2h(unsigned int c00, unsigned int c01,
                                                 unsigned int c10, unsigned int c11,
                                                 h2 w00, h2 w01, h2 w10, h2 w11) {
    h2 v00, v01, v10, v11;
    __builtin_memcpy(&v00, &c00, 4);
    __builtin_memcpy(&v01, &c01, 4);
    __builtin_memcpy(&v10, &c10, 4);
    __builtin_memcpy(&v11, &c11, 4);
    h2 r = v00 * w00 + v01 * w01 + v10 * w10 + v11 * w11;
    unsigned int o;
    __builtin_memcpy(&o, &r, 4);
    return o;
}

// ---------------------------------------------------------------------------
// Merged prep kernel (fp16 staging). Unchanged from r2/r5/r9/r10.
// ---------------------------------------------------------------------------
__global__ __launch_bounds__(256)
void prep_all(const float* __restrict__ x,
              const float* __restrict__ off_w,
              const float* __restrict__ def_w,
              short* __restrict__ xTpad,
              short* __restrict__ dwA32,
              short* __restrict__ owA)
{
    const int blk = blockIdx.x;
    const int t   = threadIdx.x;

    if (blk < 1024) {
        const int bg = blk >> 4;
        const int y0 = (blk & 15) * 4;

        __shared__ unsigned int sBw[4 * CG * 33];   // 33792 B, f16x2 packed, padded

        const float* src = x + (size_t)bg * CG * HW + (size_t)y0 * W_;
        const int i  = t >> 2;          // channel 0..63
        const int x0 = (t & 3) * 16;    // col base 0/16/32/48

        float4 v[4][4];
#pragma unroll
        for (int r = 0; r < 4; r++) {
            const float* sp = src + (size_t)i * HW + r * W_ + x0;
#pragma unroll
            for (int c = 0; c < 4; c++) v[r][c] = ((const float4*)sp)[c];
        }

#pragma unroll
        for (int r = 0; r < 4; r++) {
#pragma unroll
            for (int c = 0; c < 4; c++) {
                const unsigned int u0 = pk2h(v[r][c].x, v[r][c].y);
                const unsigned int u1 = pk2h(v[r][c].z, v[r][c].w);
                const int base = (r * CG + i) * 33 + ((x0 + 4 * c) >> 1);
                sBw[base]     = u0;
                sBw[base + 1] = u1;
            }
        }
        __syncthreads();

        const short* sBs = (const short*)sBw;
        short* dst = xTpad + (size_t)bg * XSLICE;
#pragma unroll
        for (int r = 0; r < 4; r++) {
            const int yp = y0 + 2 + r;
            for (int task = t; task < PD * 8; task += 256) {
                const int ich = task & 7;
                const int xp  = task >> 3;
                const int xx  = xp - 2;
                short8 o = {0, 0, 0, 0, 0, 0, 0, 0};
                if ((unsigned)xx < (unsigned)W_) {
#pragma unroll
                    for (int e = 0; e < 8; e++)
                        o[e] = sBs[(r * CG + ich * 8 + e) * 66 + xx];
                }
                *(short8*)(dst + ((size_t)yp * PD + xp) * CG + ich * 8) = o;
            }
        }
        return;
    }

    if (blk < 1088) {
        const int bg = blk - 1024;
        short* dstb = xTpad + (size_t)bg * XSLICE;
        const int4 z = {0, 0, 0, 0};
        int4* d0 = (int4*)(dstb);
        int4* d1 = (int4*)(dstb + (size_t)66 * PD * CG);
        const int n16 = (2 * PD * CG * 2) / 16;
        for (int c = t; c < n16; c += 256) { d0[c] = z; d1[c] = z; }
        return;
    }

    const int tid = (blk - 1088) * 256 + t;
    const int ndw = G_ * KK * 4096;               // 147456
    const int now = G_ * 18 * 2 * 4 * 16 * 8;     // 73728
    if (tid < ndw) {
        const int e    = tid & 7;
        const int o    = (tid >> 3) & 31;
        const int q2   = (tid >> 8) & 1;
        const int step = (tid >> 9) & 3;
        const int mt   = (tid >> 11) & 1;
        const int gk   = tid >> 12;
        const int k    = gk % KK;
        const int g    = gk / KK;
        const int oo   = mt * 32 + o;
        const int i    = step * 16 + q2 * 8 + e;
        dwA32[tid] = f2h(def_w[((g * CG + oo) * CG + i) * KK + k]);
    } else if (tid < ndw + now) {
        const int t2 = tid - ndw;
        const int e  = t2 & 7;
        const int jj = (t2 >> 3) & 15;
        const int q  = (t2 >> 7) & 3;
        const int tm = (t2 >> 9) & 1;
        const int gs = t2 >> 10;
        const int s  = gs % 18;
        const int g  = gs / 18;
        const int j  = tm * 16 + jj;
        const int rc = s >> 1;
        const int i  = (s & 1) * 32 + q * 8 + e;
        owA[t2] = (j < 18) ? f2h(off_w[((g * 18 + j) * CG + i) * KK + rc]) : (short)0;
    }
}

// ---------------------------------------------------------------------------
// Main fused kernel (fp16, LDS-staged weights + dbuf + transposed epilogue).
//  r10 skeleton with:
//   - sT and sW both double-buffered -> 1 barrier/tap in phase B (was 2)
//   - epilogue: acc -> LDS (stride-65-dword f32 tile, 2-way-conflict-free
//     both sides) -> coalesced float4 stores: 64 scalar-store insts -> 16.
//  VMEM wave-insts per block: 532 -> 484. LDS 39,424 B -> 4 blocks/CU.
// ---------------------------------------------------------------------------
__global__ __launch_bounds__(256, 4)
void deform_main(const short* __restrict__ xTpad,
                 const float* __restrict__ off_b,
                 const float* __restrict__ def_b,
                 const short* __restrict__ dwA32,
                 const short* __restrict__ owA,
                 float* __restrict__ out)
{
    const int raw = blockIdx.x;
    const int r8  = raw & 7;
    const int h   = (raw >> 3) & 63;
    const int q8  = raw >> 9;
    const int bg  = q8 * 8 + r8;
    const int b   = bg >> 2;
    const int g   = bg & 3;

    __shared__ float2 pcs[KK][64];          //  4,608 B
    __shared__ short  sT[2][64 * IP];       // 18,432 B (dbuf; epilogue reuses as f32)
    __shared__ short  sW[2][4096];          // 16,384 B weight stage (dbuf)

    const int t    = threadIdx.x;
    const int lane = t & 63;
    const int p    = t >> 6;          // wave id 0..3
    const int nn   = lane & 15;
    const int q    = lane >> 4;

    const short* xb = xTpad + (size_t)bg * XSLICE;

    // ---------------- Phase A: offset conv (MFMA 16x16x32 f16) ----------------
    // ow chunk for tap rc (4 KB) staged into alternating halves of sW[0].
    {
        const short* owAg = owA + g * 18 * 1024;
        f32x4 oa0 = {0.f, 0.f, 0.f, 0.f};
        f32x4 oa1 = {0.f, 0.f, 0.f, 0.f};

        *(uint4*)&sW[0][(0 & 1) * 2048 + t * 8] = *(const uint4*)(owAg + t * 8);
        __syncthreads();
#pragma unroll
        for (int rc = 0; rc < 9; rc++) {
            const int rr = rc / 3;
            const int cc = rc % 3;
            if (rc < 8)
                *(uint4*)&sW[0][((rc + 1) & 1) * 2048 + t * 8] =
                    *(const uint4*)(owAg + (rc + 1) * 2048 + t * 8);
            const short* cp = xb + ((h + rr + 1) * PD + (p * 16 + nn + cc + 1)) * CG + q * 8;
            const half8 b0 = *(const half8*)cp;          // s = 2rc   (ih=0)
            const half8 b1 = *(const half8*)(cp + 32);   // s = 2rc+1 (ih=32)
            const short* aw = &sW[0][(rc & 1) * 2048];
            const half8 a00 = *(const half8*)(aw +        q * 128 + nn * 8);
            const half8 a01 = *(const half8*)(aw +  512 + q * 128 + nn * 8);
            const half8 a10 = *(const half8*)(aw + 1024 + q * 128 + nn * 8);
            const half8 a11 = *(const half8*)(aw + 1536 + q * 128 + nn * 8);
            oa0 = __builtin_amdgcn_mfma_f32_16x16x32_f16(a00, b0, oa0, 0, 0, 0);
            oa1 = __builtin_amdgcn_mfma_f32_16x16x32_f16(a01, b0, oa1, 0, 0, 0);
            oa0 = __builtin_amdgcn_mfma_f32_16x16x32_f16(a10, b1, oa0, 0, 0, 0);
            oa1 = __builtin_amdgcn_mfma_f32_16x16x32_f16(a11, b1, oa1, 0, 0, 0);
            __syncthreads();   // stage(rc+1) complete; reads(rc) done before reuse
        }
        // C layout: col = nn (w within tile), row = q*4 + reg (j)
        const int n = p * 16 + nn;
#pragma unroll
        for (int reg = 0; reg < 4; reg++) {
            const int j  = q * 4 + reg;
            const int kk = j >> 1;
            const float v = oa0[reg] + off_b[g * 18 + j];
            if ((j & 1) == 0) pcs[kk][n].x = v + (float)(kk / 3) + (float)(h + 1);
            else              pcs[kk][n].y = v + (float)(kk % 3) + (float)(n + 1);
        }
        if (q == 0) {
            pcs[8][n].x = oa1[0] + off_b[g * 18 + 16] + 2.0f + (float)(h + 1);
            pcs[8][n].y = oa1[1] + off_b[g * 18 + 17] + 2.0f + (float)(n + 1);
        }
        // wave-private pcs columns: no barrier
    }

    // ---------------- Phase B: gather + einsum, double-buffered ---------------
    const int mt  = p >> 1;           // einsum output 32-row tile
    const int nt  = p & 1;            // einsum output 32-col tile
    const int n31 = lane & 31;
    const int q2  = lane >> 5;

    f32x16 acc = {0.f};
    const short* dwg = dwA32 + g * KK * 4096;

    const int posL  = lane >> 3;      // 0..7: position within 8-group
    const int chidx = lane & 7;       // 8-channel chunk
    const int posA  = p * 16 + posL;      // this lane's first position
    const int posB  = posA + 8;           // this lane's second position

    // in-flight gather state: NAMED variables only (rule #20: no arrays)
    uint4 ca00, ca01, ca10, ca11;
    uint4 cb00, cb01, cb10, cb11;
    float wya, wxa, wyb, wxb;

    // issue the 8 corner loads of one tap into named registers
    auto issue_g = [&](int k) {
        {
            const float2 pc = pcs[k][posA];
            const float yf = floorf(pc.x);
            const float xf = floorf(pc.y);
            wya = pc.x - yf;
            wxa = pc.y - xf;
            int y0 = (int)yf;
            int x0 = (int)xf;
            y0 = (y0 < 0) ? 0 : ((y0 > 66) ? 66 : y0);
            x0 = (x0 < 0) ? 0 : ((x0 > 66) ? 66 : x0);
            const short* cp = xb + (y0 * PD + x0) * CG + chidx * 8;
            ca00 = *(const uint4*)cp;
            ca01 = *(const uint4*)(cp + CG);
            ca10 = *(const uint4*)(cp + PD * CG);
            ca11 = *(const uint4*)(cp + PD * CG + CG);
        }
        {
            const float2 pc = pcs[k][posB];
            const float yf = floorf(pc.x);
            const float xf = floorf(pc.y);
            wyb = pc.x - yf;
            wxb = pc.y - xf;
            int y0 = (int)yf;
            int x0 = (int)xf;
            y0 = (y0 < 0) ? 0 : ((y0 > 66) ? 66 : y0);
            x0 = (x0 < 0) ? 0 : ((x0 > 66) ? 66 : x0);
            const short* cp = xb + (y0 * PD + x0) * CG + chidx * 8;
            cb00 = *(const uint4*)cp;
            cb01 = *(const uint4*)(cp + CG);
            cb10 = *(const uint4*)(cp + PD * CG);
            cb11 = *(const uint4*)(cp + PD * CG + CG);
        }
    };

    // consume the in-flight corners: packed interp + sT write
    auto write_t = [&](short* __restrict__ sTb) {
        {
            const float a00 = (1.0f - wya) * (1.0f - wxa);
            const float a01 = (1.0f - wya) * wxa;
            const float a10 = wya * (1.0f - wxa);
            const float a11 = wya * wxa;
            const h2 w00 = { (_Float16)a00, (_Float16)a00 };
            const h2 w01 = { (_Float16)a01, (_Float16)a01 };
            const h2 w10 = { (_Float16)a10, (_Float16)a10 };
            const h2 w11 = { (_Float16)a11, (_Float16)a11 };
            uint4 ov;
            ov.x = interp2h(ca00.x, ca01.x, ca10.x, ca11.x, w00, w01, w10, w11);
            ov.y = interp2h(ca00.y, ca01.y, ca10.y, ca11.y, w00, w01, w10, w11);
            ov.z = interp2h(ca00.z, ca01.z, ca10.z, ca11.z, w00, w01, w10, w11);
            ov.w = interp2h(ca00.w, ca01.w, ca10.w, ca11.w, w00, w01, w10, w11);
            *(uint4*)&sTb[posA * IP + chidx * 8] = ov;
        }
        {
            const float a00 = (1.0f - wyb) * (1.0f - wxb);
            const float a01 = (1.0f - wyb) * wxb;
            const float a10 = wyb * (1.0f - wxb);
            const float a11 = wyb * wxb;
            const h2 w00 = { (_Float16)a00, (_Float16)a00 };
            const h2 w01 = { (_Float16)a01, (_Float16)a01 };
            const h2 w10 = { (_Float16)a10, (_Float16)a10 };
            const h2 w11 = { (_Float16)a11, (_Float16)a11 };
            uint4 ov;
            ov.x = interp2h(cb00.x, cb01.x, cb10.x, cb11.x, w00, w01, w10, w11);
            ov.y = interp2h(cb00.y, cb01.y, cb10.y, cb11.y, w00, w01, w10, w11);
            ov.z = interp2h(cb00.z, cb01.z, cb10.z, cb11.z, w00, w01, w10, w11);
            ov.w = interp2h(cb00.w, cb01.w, cb10.w, cb11.w, w00, w01, w10, w11);
            *(uint4*)&sTb[posB * IP + chidx * 8] = ov;
        }
    };

    // stage tap-k weight chunk (8 KB) into sW[buf]: 2 uint4 per thread
    auto stage_af = [&](int k, short* __restrict__ sWb) {
        const short* dwk = dwg + k * 4096;
        *(uint4*)&sWb[t * 8]        = *(const uint4*)(dwk + t * 8);
        *(uint4*)&sWb[2048 + t * 8] = *(const uint4*)(dwk + 2048 + t * 8);
    };

    // einsum of one tap: af from sW[buf], bf from sT[buf]
    auto einsum_t = [&](const short* __restrict__ sTb, const short* __restrict__ sWb) {
        const half8 af0 = *(const half8*)&sWb[((mt * 4 + 0) * 2 + q2) * 256 + n31 * 8];
        const half8 af1 = *(const half8*)&sWb[((mt * 4 + 1) * 2 + q2) * 256 + n31 * 8];
        const half8 af2 = *(const half8*)&sWb[((mt * 4 + 2) * 2 + q2) * 256 + n31 * 8];
        const half8 af3 = *(const half8*)&sWb[((mt * 4 + 3) * 2 + q2) * 256 + n31 * 8];
        const half8 bf0 = *(const half8*)&sTb[(nt * 32 + n31) * IP + 0 * 16 + q2 * 8];
        const half8 bf1 = *(const half8*)&sTb[(nt * 32 + n31) * IP + 1 * 16 + q2 * 8];
        const half8 bf2 = *(const half8*)&sTb[(nt * 32 + n31) * IP + 2 * 16 + q2 * 8];
        const half8 bf3 = *(const half8*)&sTb[(nt * 32 + n31) * IP + 3 * 16 + q2 * 8];
        acc = __builtin_amdgcn_mfma_f32_32x32x16_f16(af0, bf0, acc, 0, 0, 0);
        acc = __builtin_amdgcn_mfma_f32_32x32x16_f16(af1, bf1, acc, 0, 0, 0);
        acc = __builtin_amdgcn_mfma_f32_32x32x16_f16(af2, bf2, acc, 0, 0, 0);
        acc = __builtin_amdgcn_mfma_f32_32x32x16_f16(af3, bf3, acc, 0, 0, 0);
    };

    stage_af(0, &sW[1][0]);   // tap 0 -> sW[1] so loop parity (k&1) works: use (k+1)&1
    issue_g(0);
    write_t(&sT[0][0]);
    __syncthreads();                          // sT[0] + sW[1] ready
#pragma unroll
    for (int k = 0; k < KK; k++) {
        if (k < KK - 1) {
            issue_g(k + 1);                       // gather(k+1) in flight
            stage_af(k + 1, &sW[k & 1][0]);       // af(k+1) -> other sW buffer
        }
        einsum_t(&sT[k & 1][0], &sW[(k + 1) & 1][0]);   // consume tap k
        if (k < KK - 1) write_t(&sT[(k + 1) & 1][0]);   // sT(k+1) -> other buffer
        __syncthreads();
    }

    // ---------------- epilogue: LDS transpose -> coalesced float4 stores ------
    // C/D 32x32 layout: col = lane&31, row = (reg&3) + 8*(reg>>2) + 4*q2
    float* eT = (float*)&sT[0][0];            // 64 x (stride 65) f32 = 16,640 B
    {
        const int n = nt * 32 + n31;
#pragma unroll
        for (int reg = 0; reg < 16; reg++) {
            const int o = mt * 32 + (reg & 3) + 8 * (reg >> 2) + 4 * q2;
            eT[o * 65 + n] = acc[reg];
        }
    }
    __syncthreads();
    {
        const int o    = t & 63;
        const int part = t >> 6;
        const float bias = def_b[g * 64 + o];
        float* outp = out + (size_t)(b * 256 + g * 64) * HW + h * W_ + (size_t)o * HW + part * 16;
        const float* e = &eT[o * 65 + part * 16];
#pragma unroll
        for (int j0 = 0; j0 < 4; j0++) {
            float4 r;
            r.x = e[j0 * 4 + 0] + bias;
            r.y = e[j0 * 4 + 1] + bias;
            r.z = e[j0 * 4 + 2] + bias;
            r.w = e[j0 * 4 + 3] + bias;
            *(float4*)&outp[j0 * 4] = r;
        }
    }
}

// ---------------------------------------------------------------------------
// Fallback (no workspace): round-1-style fused fp32 kernel, known correct.
// ---------------------------------------------------------------------------
__global__ __launch_bounds__(256, 4)
void deform_fallback(const float* __restrict__ x,
                     const float* __restrict__ off_w,
                     const float* __restrict__ off_b,
                     const float* __restrict__ def_w,
                     const float* __restrict__ def_b,
                     float* __restrict__ out)
{
    const int raw = blockIdx.x;
    const int r8  = raw & 7;
    const int h   = (raw >> 3) & 63;
    const int q8  = raw >> 9;
    const int bg  = q8 * 8 + r8;
    const int b   = bg >> 2;
    const int g   = bg & 3;

    __shared__ float pys[KK][W_];
    __shared__ float pxs[KK][W_];
    __shared__ float buf[8192];
    float* red   = buf;
    float* s_lds = buf;
    float* dwTl  = buf + 4096;

    const int t = threadIdx.x;
    const int w = t & 63;
    const int p = t >> 6;

    const float* xg = x + (size_t)(b * 256 + g * 64) * HW;

    float acc[18];
#pragma unroll
    for (int j = 0; j < 18; j++) acc[j] = 0.0f;
    {
        const int i0 = p * 16;
        for (int ii = 0; ii < 16; ii++) {
            const int i = i0 + ii;
            const float* xi = xg + i * HW;
#pragma unroll
            for (int r = 0; r < 3; r++) {
                const int y = h + r - 1;
                if ((unsigned)y >= (unsigned)H_) continue;
#pragma unroll
                for (int c = 0; c < 3; c++) {
                    const int xc = w + c - 1;
                    const float xv = ((unsigned)xc < (unsigned)W_) ? xi[y * W_ + xc] : 0.0f;
#pragma unroll
                    for (int j = 0; j < 18; j++) {
                        const float wv = off_w[((g * 18 + j) * CG + i) * 9 + r * 3 + c];
                        acc[j] = fmaf(wv, xv, acc[j]);
                    }
                }
            }
        }
    }
#pragma unroll
    for (int j = 0; j < 18; j++) red[(p * 18 + j) * 64 + w] = acc[j];
    __syncthreads();
    for (int idx = t; idx < 18 * 64; idx += 256) {
        const int j  = idx >> 6;
        const int ww = idx & 63;
        float v = red[(0 * 18 + j) * 64 + ww] + red[(1 * 18 + j) * 64 + ww]
                + red[(2 * 18 + j) * 64 + ww] + red[(3 * 18 + j) * 64 + ww];
        v += off_b[g * 18 + j];
        const int k = j >> 1;
        if ((j & 1) == 0) pys[k][ww] = v + (float)(k / 3 - 1) + (float)h;
        else              pxs[k][ww] = v + (float)(k % 3 - 1) + (float)ww;
    }
    __syncthreads();

    float facc[16];
#pragma unroll
    for (int qd = 0; qd < 16; qd++) facc[qd] = 0.0f;
    const int w4 = (t & 15) << 2;
    const int o4 = (t >> 4) << 2;

    for (int k = 0; k < KK; k++) {
#pragma unroll
        for (int n = 0; n < 16; n++) {
            const int v = t + 256 * n;
            const int i = v >> 6;
            const int o = v & 63;
            dwTl[v] = def_w[((g * CG + o) * CG + i) * KK + k];
        }
        const float py  = pys[k][w];
        const float px  = pxs[k][w];
        const float y0f = floorf(py);
        const float x0f = floorf(px);
        const float wy  = py - y0f;
        const float wx  = px - x0f;
        const int   y0  = (int)y0f;
        const int   x0  = (int)x0f;
        const float w00 = (1.0f - wy) * (1.0f - wx);
        const float w01 = (1.0f - wy) * wx;
        const float w10 = wy * (1.0f - wx);
        const float w11 = wy * wx;
        const bool vy0 = (unsigned)y0       < (unsigned)H_;
        const bool vy1 = (unsigned)(y0 + 1) < (unsigned)H_;
        const bool vx0 = (unsigned)x0       < (unsigned)W_;
        const bool vx1 = (unsigned)(x0 + 1) < (unsigned)W_;
        const int a00 = y0 * W_ + x0;
#pragma unroll
        for (int n = 0; n < 16; n++) {
            const int i = (n << 2) + p;
            const float* xi = xg + i * HW;
            const float v00 = (vy0 && vx0) ? xi[a00]          : 0.0f;
            const float v01 = (vy0 && vx1) ? xi[a00 + 1]      : 0.0f;
            const float v10 = (vy1 && vx0) ? xi[a00 + W_]     : 0.0f;
            const float v11 = (vy1 && vx1) ? xi[a00 + W_ + 1] : 0.0f;
            s_lds[i * 64 + w] = w00 * v00 + w01 * v01 + w10 * v10 + w11 * v11;
        }
        __syncthreads();
#pragma unroll 4
        for (int i = 0; i < CG; i++) {
            const float4 sv = *(const float4*)&s_lds[i * 64 + w4];
            const float4 dv = *(const float4*)&dwTl[i * 64 + o4];
            facc[0]  = fmaf(dv.x, sv.x, facc[0]);
            facc[1]  = fmaf(dv.x, sv.y, facc[1]);
            facc[2]  = fmaf(dv.x, sv.z, facc[2]);
            facc[3]  = fmaf(dv.x, sv.w, facc[3]);
            facc[4]  = fmaf(dv.y, sv.x, facc[4]);
            facc[5]  = fmaf(dv.y, sv.y, facc[5]);
            facc[6]  = fmaf(dv.y, sv.z, facc[6]);
            facc[7]  = fmaf(dv.y, sv.w, facc[7]);
            facc[8]  = fmaf(dv.z, sv.x, facc[8]);
            facc[9]  = fmaf(dv.z, sv.y, facc[9]);
            facc[10] = fmaf(dv.z, sv.z, facc[10]);
            facc[11] = fmaf(dv.z, sv.w, facc[11]);
            facc[12] = fmaf(dv.w, sv.x, facc[12]);
            facc[13] = fmaf(dv.w, sv.y, facc[13]);
            facc[14] = fmaf(dv.w, sv.z, facc[14]);
            facc[15] = fmaf(dv.w, sv.w, facc[15]);
        }
        __syncthreads();
    }

    float* outp = out + (size_t)(b * 256 + g * 64) * HW + h * W_;
#pragma unroll
    for (int oo = 0; oo < 4; oo++) {
        const int o = o4 + oo;
        const float bias = def_b[g * 64 + o];
        float4 r;
        r.x = facc[oo * 4 + 0] + bias;
        r.y = facc[oo * 4 + 1] + bias;
        r.z = facc[oo * 4 + 2] + bias;
        r.w = facc[oo * 4 + 3] + bias;
        *(float4*)&outp[o * HW + w4] = r;
    }
}

// ---------------------------------------------------------------------------
extern "C" void kernel_launch(void* const* d_in, const int* in_sizes, int n_in,
                              void* d_out, int out_size, void* d_ws, size_t ws_size,
                              hipStream_t stream)
{
    (void)in_sizes; (void)n_in; (void)out_size;
    const float* x     = (const float*)d_in[0];
    const float* off_w = (const float*)d_in[1];
    const float* off_b = (const float*)d_in[2];
    const float* def_w = (const float*)d_in[3];
    const float* def_b = (const float*)d_in[4];
    float* out = (float*)d_out;

    const size_t xT_bytes  = (size_t)B_ * G_ * XSLICE * 2;     // 37,879,808
    const size_t dw_bytes  = (size_t)G_ * KK * 4096 * 2;       // 294,912
    const size_t ow_bytes  = (size_t)G_ * 18 * 1024 * 2;       // 147,456
    const size_t need = xT_bytes + dw_bytes + ow_bytes;

    const int nblk   = B_ * G_ * H_;                     // 4096
    const int nprepw = (G_ * KK * 4096 + G_ * 18 * 1024 + 255) / 256;  // 864
    const int nprep  = 1024 + 64 + nprepw;               // x-tiles + zero rows + weights

    if (ws_size >= need) {
        short* xTpad = (short*)d_ws;
        short* dwA32 = (short*)((char*)d_ws + xT_bytes);
        short* owA   = (short*)((char*)d_ws + xT_bytes + dw_bytes);
        prep_all<<<nprep, 256, 0, stream>>>(x, off_w, def_w, xTpad, dwA32, owA);
        deform_main<<<nblk, 256, 0, stream>>>(xTpad, off_b, def_b, dwA32, owA, out);
    } else {
        deform_fallback<<<nblk, 256, 0, stream>>>(x, off_w, off_b, def_w, def_b, out);
    }
}

// Round 12
// 201.060 us; speedup vs baseline: 1.0375x; 1.0375x over previous
//
#include <hip/hip_runtime.h>
#include <hip/hip_bf16.h>
#include <hip/hip_fp16.h>

#define B_  16
#define G_  4
#define CG  64
#define H_  64
#define W_  64
#define KK  9
#define HW  (H_ * W_)
#define IP  72            // padded i-stride (shorts) for sT rows: 144 B
#define PD  68            // padded spatial dim (64 + 2 each side)
#define XSLICE (PD * PD * CG)   // shorts per (b,g) slice of xTpad

typedef short    short8  __attribute__((ext_vector_type(8)));
typedef _Float16 half8   __attribute__((ext_vector_type(8)));
typedef _Float16 h2      __attribute__((ext_vector_type(2)));
typedef float    f32x4   __attribute__((ext_vector_type(4)));
typedef float    f32x16  __attribute__((ext_vector_type(16)));

__device__ __forceinline__ short f2h(float v) {
    _Float16 h = (_Float16)v;
    short s;
    __builtin_memcpy(&s, &h, 2);
    return s;
}

__device__ __forceinline__ unsigned int pk2h(float a, float b) {
    h2 h = { (_Float16)a, (_Float16)b };
    unsigned int u;
    __builtin_memcpy(&u, &h, 4);
    return u;
}

// bilinear combine of 2 packed fp16 channels via native v_pk_fma_f16
__device__ __forceinline__ unsigned int interp2h(unsigned int c00, unsigned int c01,
                                                 unsigned int c10, unsigned int c11,
                                                 h2 w00, h2 w01, h2 w10, h2 w11) {
    h2 v00, v01, v10, v11;
    __builtin_memcpy(&v00, &c00, 4);
    __builtin_memcpy(&v01, &c01, 4);
    __builtin_memcpy(&v10, &c10, 4);
    __builtin_memcpy(&v11, &c11, 4);
    h2 r = v00 * w00 + v01 * w01 + v10 * w10 + v11 * w11;
    unsigned int o;
    __builtin_memcpy(&o, &r, 4);
    return o;
}

// ---------------------------------------------------------------------------
// Merged prep kernel (fp16 staging). Unchanged from r2/r5/r9/r10.
// ---------------------------------------------------------------------------
__global__ __launch_bounds__(256)
void prep_all(const float* __restrict__ x,
              const float* __restrict__ off_w,
              const float* __restrict__ def_w,
              short* __restrict__ xTpad,
              short* __restrict__ dwA32,
              short* __restrict__ owA)
{
    const int blk = blockIdx.x;
    const int t   = threadIdx.x;

    if (blk < 1024) {
        const int bg = blk >> 4;
        const int y0 = (blk & 15) * 4;

        __shared__ unsigned int sBw[4 * CG * 33];   // 33792 B, f16x2 packed, padded

        const float* src = x + (size_t)bg * CG * HW + (size_t)y0 * W_;
        const int i  = t >> 2;          // channel 0..63
        const int x0 = (t & 3) * 16;    // col base 0/16/32/48

        float4 v[4][4];
#pragma unroll
        for (int r = 0; r < 4; r++) {
            const float* sp = src + (size_t)i * HW + r * W_ + x0;
#pragma unroll
            for (int c = 0; c < 4; c++) v[r][c] = ((const float4*)sp)[c];
        }

#pragma unroll
        for (int r = 0; r < 4; r++) {
#pragma unroll
            for (int c = 0; c < 4; c++) {
                const unsigned int u0 = pk2h(v[r][c].x, v[r][c].y);
                const unsigned int u1 = pk2h(v[r][c].z, v[r][c].w);
                const int base = (r * CG + i) * 33 + ((x0 + 4 * c) >> 1);
                sBw[base]     = u0;
                sBw[base + 1] = u1;
            }
        }
        __syncthreads();

        const short* sBs = (const short*)sBw;
        short* dst = xTpad + (size_t)bg * XSLICE;
#pragma unroll
        for (int r = 0; r < 4; r++) {
            const int yp = y0 + 2 + r;
            for (int task = t; task < PD * 8; task += 256) {
                const int ich = task & 7;
                const int xp  = task >> 3;
                const int xx  = xp - 2;
                short8 o = {0, 0, 0, 0, 0, 0, 0, 0};
                if ((unsigned)xx < (unsigned)W_) {
#pragma unroll
                    for (int e = 0; e < 8; e++)
                        o[e] = sBs[(r * CG + ich * 8 + e) * 66 + xx];
                }
                *(short8*)(dst + ((size_t)yp * PD + xp) * CG + ich * 8) = o;
            }
        }
        return;
    }

    if (blk < 1088) {
        const int bg = blk - 1024;
        short* dstb = xTpad + (size_t)bg * XSLICE;
        const int4 z = {0, 0, 0, 0};
        int4* d0 = (int4*)(dstb);
        int4* d1 = (int4*)(dstb + (size_t)66 * PD * CG);
        const int n16 = (2 * PD * CG * 2) / 16;
        for (int c = t; c < n16; c += 256) { d0[c] = z; d1[c] = z; }
        return;
    }

    const int tid = (blk - 1088) * 256 + t;
    const int ndw = G_ * KK * 4096;               // 147456
    const int now = G_ * 18 * 2 * 4 * 16 * 8;     // 73728
    if (tid < ndw) {
        const int e    = tid & 7;
        const int o    = (tid >> 3) & 31;
        const int q2   = (tid >> 8) & 1;
        const int step = (tid >> 9) & 3;
        const int mt   = (tid >> 11) & 1;
        const int gk   = tid >> 12;
        const int k    = gk % KK;
        const int g    = gk / KK;
        const int oo   = mt * 32 + o;
        const int i    = step * 16 + q2 * 8 + e;
        dwA32[tid] = f2h(def_w[((g * CG + oo) * CG + i) * KK + k]);
    } else if (tid < ndw + now) {
        const int t2 = tid - ndw;
        const int e  = t2 & 7;
        const int jj = (t2 >> 3) & 15;
        const int q  = (t2 >> 7) & 3;
        const int tm = (t2 >> 9) & 1;
        const int gs = t2 >> 10;
        const int s  = gs % 18;
        const int g  = gs / 18;
        const int j  = tm * 16 + jj;
        const int rc = s >> 1;
        const int i  = (s & 1) * 32 + q * 8 + e;
        owA[t2] = (j < 18) ? f2h(off_w[((g * 18 + j) * CG + i) * KK + rc]) : (short)0;
    }
}

// ---------------------------------------------------------------------------
// Main fused kernel (fp16, r10 structure + pooled coalesced epilogue).
//  Phase A/B identical to r10 (103.2 us): LDS-staged weights, single-buffered
//  sT/sW, 2 barriers/tap. sT+sW now live in one 17,408-B pool; after the last
//  einsum the pool is reused as a 64 x (stride 65) f32 tile so the epilogue
//  becomes 16 sectored float4 stores instead of 64 scalar stores.
//  LDS total unchanged: 22,016 B -> 7 blocks/CU.
// ---------------------------------------------------------------------------
__global__ __launch_bounds__(256, 4)
void deform_main(const short* __restrict__ xTpad,
                 const float* __restrict__ off_b,
                 const float* __restrict__ def_b,
                 const short* __restrict__ dwA32,
                 const short* __restrict__ owA,
                 float* __restrict__ out)
{
    const int raw = blockIdx.x;
    const int r8  = raw & 7;
    const int h   = (raw >> 3) & 63;
    const int q8  = raw >> 9;
    const int bg  = q8 * 8 + r8;
    const int b   = bg >> 2;
    const int g   = bg & 3;

    __shared__ float2 pcs[KK][64];          //  4,608 B
    __shared__ short  sPool[8704];          // 17,408 B: sT [0,4608), sW [4608,8704)

    short* sT = sPool;
    short* sW = sPool + 64 * IP;

    const int t    = threadIdx.x;
    const int lane = t & 63;
    const int p    = t >> 6;          // wave id 0..3
    const int nn   = lane & 15;
    const int q    = lane >> 4;

    const short* xb = xTpad + (size_t)bg * XSLICE;

    // ---------------- Phase A: offset conv (MFMA 16x16x32 f16) ----------------
    // ow chunk for tap rc (4 KB) staged into alternating halves of sW.
    {
        const short* owAg = owA + g * 18 * 1024;
        f32x4 oa0 = {0.f, 0.f, 0.f, 0.f};
        f32x4 oa1 = {0.f, 0.f, 0.f, 0.f};

        *(uint4*)&sW[(0 & 1) * 2048 + t * 8] = *(const uint4*)(owAg + t * 8);
        __syncthreads();
#pragma unroll
        for (int rc = 0; rc < 9; rc++) {
            const int rr = rc / 3;
            const int cc = rc % 3;
            if (rc < 8)
                *(uint4*)&sW[((rc + 1) & 1) * 2048 + t * 8] =
                    *(const uint4*)(owAg + (rc + 1) * 2048 + t * 8);
            const short* cp = xb + ((h + rr + 1) * PD + (p * 16 + nn + cc + 1)) * CG + q * 8;
            const half8 b0 = *(const half8*)cp;          // s = 2rc   (ih=0)
            const half8 b1 = *(const half8*)(cp + 32);   // s = 2rc+1 (ih=32)
            const short* aw = &sW[(rc & 1) * 2048];
            const half8 a00 = *(const half8*)(aw +        q * 128 + nn * 8);
            const half8 a01 = *(const half8*)(aw +  512 + q * 128 + nn * 8);
            const half8 a10 = *(const half8*)(aw + 1024 + q * 128 + nn * 8);
            const half8 a11 = *(const half8*)(aw + 1536 + q * 128 + nn * 8);
            oa0 = __builtin_amdgcn_mfma_f32_16x16x32_f16(a00, b0, oa0, 0, 0, 0);
            oa1 = __builtin_amdgcn_mfma_f32_16x16x32_f16(a01, b0, oa1, 0, 0, 0);
            oa0 = __builtin_amdgcn_mfma_f32_16x16x32_f16(a10, b1, oa0, 0, 0, 0);
            oa1 = __builtin_amdgcn_mfma_f32_16x16x32_f16(a11, b1, oa1, 0, 0, 0);
            __syncthreads();   // stage(rc+1) complete; reads(rc) done before reuse
        }
        // C layout: col = nn (w within tile), row = q*4 + reg (j)
        const int n = p * 16 + nn;
#pragma unroll
        for (int reg = 0; reg < 4; reg++) {
            const int j  = q * 4 + reg;
            const int kk = j >> 1;
            const float v = oa0[reg] + off_b[g * 18 + j];
            if ((j & 1) == 0) pcs[kk][n].x = v + (float)(kk / 3) + (float)(h + 1);
            else              pcs[kk][n].y = v + (float)(kk % 3) + (float)(n + 1);
        }
        if (q == 0) {
            pcs[8][n].x = oa1[0] + off_b[g * 18 + 16] + 2.0f + (float)(h + 1);
            pcs[8][n].y = oa1[1] + off_b[g * 18 + 17] + 2.0f + (float)(n + 1);
        }
        // wave-private pcs columns: no barrier
    }

    // ---------------- Phase B: gather + einsum, single-buffered ---------------
    const int mt  = p >> 1;           // einsum output 32-row tile
    const int nt  = p & 1;            // einsum output 32-col tile
    const int n31 = lane & 31;
    const int q2  = lane >> 5;

    f32x16 acc = {0.f};
    const short* dwg = dwA32 + g * KK * 4096;

    const int posL  = lane >> 3;      // 0..7: position within 8-group
    const int chidx = lane & 7;       // 8-channel chunk
    const int posA  = p * 16 + posL;      // this lane's first position
    const int posB  = posA + 8;           // this lane's second position

    // in-flight gather state: NAMED variables only (rule #20: no arrays)
    uint4 ca00, ca01, ca10, ca11;
    uint4 cb00, cb01, cb10, cb11;
    float wya, wxa, wyb, wxb;

    // issue the 8 corner loads of one tap into named registers
    auto issue_g = [&](int k) {
        {
            const float2 pc = pcs[k][posA];
            const float yf = floorf(pc.x);
            const float xf = floorf(pc.y);
            wya = pc.x - yf;
            wxa = pc.y - xf;
            int y0 = (int)yf;
            int x0 = (int)xf;
            y0 = (y0 < 0) ? 0 : ((y0 > 66) ? 66 : y0);
            x0 = (x0 < 0) ? 0 : ((x0 > 66) ? 66 : x0);
            const short* cp = xb + (y0 * PD + x0) * CG + chidx * 8;
            ca00 = *(const uint4*)cp;
            ca01 = *(const uint4*)(cp + CG);
            ca10 = *(const uint4*)(cp + PD * CG);
            ca11 = *(const uint4*)(cp + PD * CG + CG);
        }
        {
            const float2 pc = pcs[k][posB];
            const float yf = floorf(pc.x);
            const float xf = floorf(pc.y);
            wyb = pc.x - yf;
            wxb = pc.y - xf;
            int y0 = (int)yf;
            int x0 = (int)xf;
            y0 = (y0 < 0) ? 0 : ((y0 > 66) ? 66 : y0);
            x0 = (x0 < 0) ? 0 : ((x0 > 66) ? 66 : x0);
            const short* cp = xb + (y0 * PD + x0) * CG + chidx * 8;
            cb00 = *(const uint4*)cp;
            cb01 = *(const uint4*)(cp + CG);
            cb10 = *(const uint4*)(cp + PD * CG);
            cb11 = *(const uint4*)(cp + PD * CG + CG);
        }
    };

    // consume the in-flight corners: packed interp + sT write
    auto write_t = [&]() {
        {
            const float a00 = (1.0f - wya) * (1.0f - wxa);
            const float a01 = (1.0f - wya) * wxa;
            const float a10 = wya * (1.0f - wxa);
            const float a11 = wya * wxa;
            const h2 w00 = { (_Float16)a00, (_Float16)a00 };
            const h2 w01 = { (_Float16)a01, (_Float16)a01 };
            const h2 w10 = { (_Float16)a10, (_Float16)a10 };
            const h2 w11 = { (_Float16)a11, (_Float16)a11 };
            uint4 ov;
            ov.x = interp2h(ca00.x, ca01.x, ca10.x, ca11.x, w00, w01, w10, w11);
            ov.y = interp2h(ca00.y, ca01.y, ca10.y, ca11.y, w00, w01, w10, w11);
            ov.z = interp2h(ca00.z, ca01.z, ca10.z, ca11.z, w00, w01, w10, w11);
            ov.w = interp2h(ca00.w, ca01.w, ca10.w, ca11.w, w00, w01, w10, w11);
            *(uint4*)&sT[posA * IP + chidx * 8] = ov;
        }
        {
            const float a00 = (1.0f - wyb) * (1.0f - wxb);
            const float a01 = (1.0f - wyb) * wxb;
            const float a10 = wyb * (1.0f - wxb);
            const float a11 = wyb * wxb;
            const h2 w00 = { (_Float16)a00, (_Float16)a00 };
            const h2 w01 = { (_Float16)a01, (_Float16)a01 };
            const h2 w10 = { (_Float16)a10, (_Float16)a10 };
            const h2 w11 = { (_Float16)a11, (_Float16)a11 };
            uint4 ov;
            ov.x = interp2h(cb00.x, cb01.x, cb10.x, cb11.x, w00, w01, w10, w11);
            ov.y = interp2h(cb00.y, cb01.y, cb10.y, cb11.y, w00, w01, w10, w11);
            ov.z = interp2h(cb00.z, cb01.z, cb10.z, cb11.z, w00, w01, w10, w11);
            ov.w = interp2h(cb00.w, cb01.w, cb10.w, cb11.w, w00, w01, w10, w11);
            *(uint4*)&sT[posB * IP + chidx * 8] = ov;
        }
    };

    // stage tap-k weight chunk (8 KB) into sW: 2 uint4 per thread, coalesced
    auto stage_af = [&](int k) {
        const short* dwk = dwg + k * 4096;
        *(uint4*)&sW[t * 8]        = *(const uint4*)(dwk + t * 8);
        *(uint4*)&sW[2048 + t * 8] = *(const uint4*)(dwk + 2048 + t * 8);
    };

    // einsum of one tap: af from LDS (conflict-free contiguous), bf from sT
    auto einsum_t = [&]() {
        const half8 af0 = *(const half8*)&sW[((mt * 4 + 0) * 2 + q2) * 256 + n31 * 8];
        const half8 af1 = *(const half8*)&sW[((mt * 4 + 1) * 2 + q2) * 256 + n31 * 8];
        const half8 af2 = *(const half8*)&sW[((mt * 4 + 2) * 2 + q2) * 256 + n31 * 8];
        const half8 af3 = *(const half8*)&sW[((mt * 4 + 3) * 2 + q2) * 256 + n31 * 8];
        const half8 bf0 = *(const half8*)&sT[(nt * 32 + n31) * IP + 0 * 16 + q2 * 8];
        const half8 bf1 = *(const half8*)&sT[(nt * 32 + n31) * IP + 1 * 16 + q2 * 8];
        const half8 bf2 = *(const half8*)&sT[(nt * 32 + n31) * IP + 2 * 16 + q2 * 8];
        const half8 bf3 = *(const half8*)&sT[(nt * 32 + n31) * IP + 3 * 16 + q2 * 8];
        acc = __builtin_amdgcn_mfma_f32_32x32x16_f16(af0, bf0, acc, 0, 0, 0);
        acc = __builtin_amdgcn_mfma_f32_32x32x16_f16(af1, bf1, acc, 0, 0, 0);
        acc = __builtin_amdgcn_mfma_f32_32x32x16_f16(af2, bf2, acc, 0, 0, 0);
        acc = __builtin_amdgcn_mfma_f32_32x32x16_f16(af3, bf3, acc, 0, 0, 0);
    };

    stage_af(0);                              // phase A reads of sW done (barrier'd)
    issue_g(0);
    write_t();
    __syncthreads();                          // sT[0] + af[0] ready
#pragma unroll
    for (int k = 0; k < KK; k++) {
        if (k < KK - 1) issue_g(k + 1);       // next tap's gather in flight
        einsum_t();                           // consume sT + sW
        if (k < KK - 1) {
            __syncthreads();                  // all reads of sT/sW complete
            write_t();                        // overwrite sT with tap k+1
            stage_af(k + 1);                  // overwrite sW with tap k+1
            __syncthreads();                  // sT[k+1] + af[k+1] ready
        }
    }

    // ---------------- epilogue: pooled LDS transpose -> sectored f4 stores ----
    // C/D 32x32 layout: col = lane&31, row = (reg&3) + 8*(reg>>2) + 4*q2
    __syncthreads();                          // all einsum reads of pool done
    float* eT = (float*)sPool;                // 64 x (stride 65) f32 = 16,640 B
    {
        const int n = nt * 32 + n31;
#pragma unroll
        for (int reg = 0; reg < 16; reg++) {
            const int o = mt * 32 + (reg & 3) + 8 * (reg >> 2) + 4 * q2;
            eT[o * 65 + n] = acc[reg];
        }
    }
    __syncthreads();
    {
        const int row = t >> 2;               // output channel o
        const int c4  = (t & 3) * 4;          // sub-sector base
        const float bias = def_b[g * 64 + row];
        float* outp = out + (size_t)(b * 256 + g * 64) * HW + h * W_ + (size_t)row * HW;
        const float* e = &eT[row * 65];
#pragma unroll
        for (int j0 = 0; j0 < 4; j0++) {
            const int c = c4 + j0 * 16;       // per-inst: lanes 0..3 cover 64 B
            float4 r;
            r.x = e[c + 0] + bias;
            r.y = e[c + 1] + bias;
            r.z = e[c + 2] + bias;
            r.w = e[c + 3] + bias;
            *(float4*)&outp[c] = r;
        }
    }
}

// ---------------------------------------------------------------------------
// Fallback (no workspace): round-1-style fused fp32 kernel, known correct.
// ---------------------------------------------------------------------------
__global__ __launch_bounds__(256, 4)
void deform_fallback(const float* __restrict__ x,
                     const float* __restrict__ off_w,
                     const float* __restrict__ off_b,
                     const float* __restrict__ def_w,
                     const float* __restrict__ def_b,
                     float* __restrict__ out)
{
    const int raw = blockIdx.x;
    const int r8  = raw & 7;
    const int h   = (raw >> 3) & 63;
    const int q8  = raw >> 9;
    const int bg  = q8 * 8 + r8;
    const int b   = bg >> 2;
    const int g   = bg & 3;

    __shared__ float pys[KK][W_];
    __shared__ float pxs[KK][W_];
    __shared__ float buf[8192];
    float* red   = buf;
    float* s_lds = buf;
    float* dwTl  = buf + 4096;

    const int t = threadIdx.x;
    const int w = t & 63;
    const int p = t >> 6;

    const float* xg = x + (size_t)(b * 256 + g * 64) * HW;

    float acc[18];
#pragma unroll
    for (int j = 0; j < 18; j++) acc[j] = 0.0f;
    {
        const int i0 = p * 16;
        for (int ii = 0; ii < 16; ii++) {
            const int i = i0 + ii;
            const float* xi = xg + i * HW;
#pragma unroll
            for (int r = 0; r < 3; r++) {
                const int y = h + r - 1;
                if ((unsigned)y >= (unsigned)H_) continue;
#pragma unroll
                for (int c = 0; c < 3; c++) {
                    const int xc = w + c - 1;
                    const float xv = ((unsigned)xc < (unsigned)W_) ? xi[y * W_ + xc] : 0.0f;
#pragma unroll
                    for (int j = 0; j < 18; j++) {
                        const float wv = off_w[((g * 18 + j) * CG + i) * 9 + r * 3 + c];
                        acc[j] = fmaf(wv, xv, acc[j]);
                    }
                }
            }
        }
    }
#pragma unroll
    for (int j = 0; j < 18; j++) red[(p * 18 + j) * 64 + w] = acc[j];
    __syncthreads();
    for (int idx = t; idx < 18 * 64; idx += 256) {
        const int j  = idx >> 6;
        const int ww = idx & 63;
        float v = red[(0 * 18 + j) * 64 + ww] + red[(1 * 18 + j) * 64 + ww]
                + red[(2 * 18 + j) * 64 + ww] + red[(3 * 18 + j) * 64 + ww];
        v += off_b[g * 18 + j];
        const int k = j >> 1;
        if ((j & 1) == 0) pys[k][ww] = v + (float)(k / 3 - 1) + (float)h;
        else              pxs[k][ww] = v + (float)(k % 3 - 1) + (float)ww;
    }
    __syncthreads();

    float facc[16];
#pragma unroll
    for (int qd = 0; qd < 16; qd++) facc[qd] = 0.0f;
    const int w4 = (t & 15) << 2;
    const int o4 = (t >> 4) << 2;

    for (int k = 0; k < KK; k++) {
#pragma unroll
        for (int n = 0; n < 16; n++) {
            const int v = t + 256 * n;
            const int i = v >> 6;
            const int o = v & 63;
            dwTl[v] = def_w[((g * CG + o) * CG + i) * KK + k];
        }
        const float py  = pys[k][w];
        const float px  = pxs[k][w];
        const float y0f = floorf(py);
        const float x0f = floorf(px);
        const float wy  = py - y0f;
        const float wx  = px - x0f;
        const int   y0  = (int)y0f;
        const int   x0  = (int)x0f;
        const float w00 = (1.0f - wy) * (1.0f - wx);
        const float w01 = (1.0f - wy) * wx;
        const float w10 = wy * (1.0f - wx);
        const float w11 = wy * wx;
        const bool vy0 = (unsigned)y0       < (unsigned)H_;
        const bool vy1 = (unsigned)(y0 + 1) < (unsigned)H_;
        const bool vx0 = (unsigned)x0       < (unsigned)W_;
        const bool vx1 = (unsigned)(x0 + 1) < (unsigned)W_;
        const int a00 = y0 * W_ + x0;
#pragma unroll
        for (int n = 0; n < 16; n++) {
            const int i = (n << 2) + p;
            const float* xi = xg + i * HW;
            const float v00 = (vy0 && vx0) ? xi[a00]          : 0.0f;
            const float v01 = (vy0 && vx1) ? xi[a00 + 1]      : 0.0f;
            const float v10 = (vy1 && vx0) ? xi[a00 + W_]     : 0.0f;
            const float v11 = (vy1 && vx1) ? xi[a00 + W_ + 1] : 0.0f;
            s_lds[i * 64 + w] = w00 * v00 + w01 * v01 + w10 * v10 + w11 * v11;
        }
        __syncthreads();
#pragma unroll 4
        for (int i = 0; i < CG; i++) {
            const float4 sv = *(const float4*)&s_lds[i * 64 + w4];
            const float4 dv = *(const float4*)&dwTl[i * 64 + o4];
            facc[0]  = fmaf(dv.x, sv.x, facc[0]);
            facc[1]  = fmaf(dv.x, sv.y, facc[1]);
            facc[2]  = fmaf(dv.x, sv.z, facc[2]);
            facc[3]  = fmaf(dv.x, sv.w, facc[3]);
            facc[4]  = fmaf(dv.y, sv.x, facc[4]);
            facc[5]  = fmaf(dv.y, sv.y, facc[5]);
            facc[6]  = fmaf(dv.y, sv.z, facc[6]);
            facc[7]  = fmaf(dv.y, sv.w, facc[7]);
            facc[8]  = fmaf(dv.z, sv.x, facc[8]);
            facc[9]  = fmaf(dv.z, sv.y, facc[9]);
            facc[10] = fmaf(dv.z, sv.z, facc[10]);
            facc[11] = fmaf(dv.z, sv.w, facc[11]);
            facc[12] = fmaf(dv.w, sv.x, facc[12]);
            facc[13] = fmaf(dv.w, sv.y, facc[13]);
            facc[14] = fmaf(dv.w, sv.z, facc[14]);
            facc[15] = fmaf(dv.w, sv.w, facc[15]);
        }
        __syncthreads();
    }

    float* outp = out + (size_t)(b * 256 + g * 64) * HW + h * W_;
#pragma unroll
    for (int oo = 0; oo < 4; oo++) {
        const int o = o4 + oo;
        const float bias = def_b[g * 64 + o];
        float4 r;
        r.x = facc[oo * 4 + 0] + bias;
        r.y = facc[oo * 4 + 1] + bias;
        r.z = facc[oo * 4 + 2] + bias;
        r.w = facc[oo * 4 + 3] + bias;
        *(float4*)&outp[o * HW + w4] = r;
    }
}

// ---------------------------------------------------------------------------
extern "C" void kernel_launch(void* const* d_in, const int* in_sizes, int n_in,
                              void* d_out, int out_size, void* d_ws, size_t ws_size,
                              hipStream_t stream)
{
    (void)in_sizes; (void)n_in; (void)out_size;
    const float* x     = (const float*)d_in[0];
    const float* off_w = (const float*)d_in[1];
    const float* off_b = (const float*)d_in[2];
    const float* def_w = (const float*)d_in[3];
    const float* def_b = (const float*)d_in[4];
    float* out = (float*)d_out;

    const size_t xT_bytes  = (size_t)B_ * G_ * XSLICE * 2;     // 37,879,808
    const size_t dw_bytes  = (size_t)G_ * KK * 4096 * 2;       // 294,912
    const size_t ow_bytes  = (size_t)G_ * 18 * 1024 * 2;       // 147,456
    const size_t need = xT_bytes + dw_bytes + ow_bytes;

    const int nblk   = B_ * G_ * H_;                     // 4096
    const int nprepw = (G_ * KK * 4096 + G_ * 18 * 1024 + 255) / 256;  // 864
    const int nprep  = 1024 + 64 + nprepw;               // x-tiles + zero rows + weights

    if (ws_size >= need) {
        short* xTpad = (short*)d_ws;
        short* dwA32 = (short*)((char*)d_ws + xT_bytes);
        short* owA   = (short*)((char*)d_ws + xT_bytes + dw_bytes);
        prep_all<<<nprep, 256, 0, stream>>>(x, off_w, def_w, xTpad, dwA32, owA);
        deform_main<<<nblk, 256, 0, stream>>>(xTpad, off_b, def_b, dwA32, owA, out);
    } else {
        deform_fallback<<<nblk, 256, 0, stream>>>(x, off_w, off_b, def_w, def_b, out);
    }
}